// Round 2
// baseline (66.467 us; speedup 1.0000x reference)
//
#include <hip/hip_runtime.h>

// MultiLabelAdaptiveMarginLoss: B=256, C=4096, K=32
// loss = (1/C) * sum_{b,k valid} sum_{j != t} relu(1 + (m_t - m_j) - (x_t - x_j))
// Rewrite: diff = a_k + c_j with a_k = 1 + m_t - x_t (per target),
//          c_j = x_j - m_j (per class). j==t term is relu(1)=1, so sum over
//          all j and subtract 1 per valid target.
// Fused single kernel: block b = row b; 1024 threads; each thread holds one
// float4 of c in registers (no LDS staging); a_k broadcast via LDS; block
// partial atomically added to d_out (zeroed by a 4-byte async memset).

#define BB 256
#define CC 4096
#define KK 32
#define THREADS 1024
#define NWAVES (THREADS / 64)

__global__ __launch_bounds__(THREADS) void mlam_fused(
    const float* __restrict__ input,
    const float* __restrict__ margin,
    const int* __restrict__ target,
    float* __restrict__ out) {

    __shared__ float sa[KK];       // a_k (=-1e30f for padded targets)
    __shared__ int   svalid;
    __shared__ float swave[NWAVES];

    const int b   = blockIdx.x;
    const int tid = threadIdx.x;
    const float* in_row = input  + (size_t)b * CC;
    const float* mg_row = margin + (size_t)b * CC;

    // Each thread owns exactly one float4 of the row: c = x - m, in registers.
    float4 x = ((const float4*)in_row)[tid];
    float4 m = ((const float4*)mg_row)[tid];
    float4 c = make_float4(x.x - m.x, x.y - m.y, x.z - m.z, x.w - m.w);

    if (tid == 0) svalid = 0;
    __syncthreads();   // svalid init visible before atomicAdd below

    // Lanes 0..31 gather per-target scalars (random-access, small).
    if (tid < KK) {
        int t = target[b * KK + tid];
        if (t >= 0) {
            sa[tid] = 1.0f + mg_row[t] - in_row[t];
            atomicAdd(&svalid, 1);
        } else {
            sa[tid] = -1e30f;   // relu(a+c) == 0 for every class j
        }
    }
    __syncthreads();

    // Broadcast a_k (LDS same-address broadcast, no conflicts).
    float a[KK];
#pragma unroll
    for (int k = 0; k < KK; ++k) a[k] = sa[k];

    // 32 targets x 4 elements; 4 independent accumulator chains.
    float acc0 = 0.f, acc1 = 0.f, acc2 = 0.f, acc3 = 0.f;
#pragma unroll
    for (int k = 0; k < KK; ++k) {
        float ak = a[k];
        acc0 += fmaxf(ak + c.x, 0.0f);
        acc1 += fmaxf(ak + c.y, 0.0f);
        acc2 += fmaxf(ak + c.z, 0.0f);
        acc3 += fmaxf(ak + c.w, 0.0f);
    }
    float acc = (acc0 + acc1) + (acc2 + acc3);

    // Wave64 shuffle reduce, then cross-wave via LDS.
#pragma unroll
    for (int off = 32; off > 0; off >>= 1)
        acc += __shfl_down(acc, off, 64);
    if ((tid & 63) == 0) swave[tid >> 6] = acc;
    __syncthreads();
    if (tid == 0) {
        float tot = 0.0f;
#pragma unroll
        for (int w = 0; w < NWAVES; ++w) tot += swave[w];
        atomicAdd(out, (tot - (float)svalid) * (1.0f / (float)CC));
    }
}

extern "C" void kernel_launch(void* const* d_in, const int* in_sizes, int n_in,
                              void* d_out, int out_size, void* d_ws, size_t ws_size,
                              hipStream_t stream) {
    const float* input  = (const float*)d_in[0];   // [B, C] fp32
    const float* margin = (const float*)d_in[1];   // [B, C] fp32
    const int*   target = (const int*)d_in[2];     // [B, K] int32
    float* out = (float*)d_out;                    // scalar fp32

    hipMemsetAsync(out, 0, sizeof(float), stream); // d_out is poisoned 0xAA
    mlam_fused<<<BB, THREADS, 0, stream>>>(input, margin, target, out);
}